// Round 4
// baseline (5930.384 us; speedup 1.0000x reference)
//
#include <hip/hip_runtime.h>
#include <hip/hip_bf16.h>

// Problem constants (from reference)
#define NA 35
#define NM 18
#define NN 53          // NA+NM
#define TT 48
#define HH 32
// output: h_aqi [1024,35,32] then h_meo [1024,18,32]
#define OUT_MEO_BASE (1024*35*32)

typedef unsigned short u16;

__device__ __forceinline__ float bf(u16 u){ return __uint_as_float(((unsigned)u)<<16); }
__device__ __forceinline__ float dot4(float4 a, float4 b){
  return a.x*b.x + a.y*b.y + a.z*b.z + a.w*b.w;
}

struct Params {
  const void *X_aqi, *X_meo, *ctx, *adj, *adjn;
  const void *emb0,*emb1,*emb2,*emb3,*emb4,*emb5,*emb6,*emb7,*emb8;
  const void *Wxa,*Wxm,*Wua,*Wum;
  const void *a0,*a1,*a2,*a3;   // a_aa, a_am, a_ma, a_mm
  const void *wih_a,*whh_a,*bih_a,*bhh_a,*wih_m,*whh_m,*bih_m,*bhh_m;
  const int *Xae,*Xme;
  void* out;
};

// dtype-agnostic float load: fp32 buffer or bf16 buffer, chosen at runtime.
__device__ __forceinline__ float ldf(const void* p, int i, bool isbf){
  return isbf ? bf(((const u16*)p)[i]) : ((const float*)p)[i];
}

// ~111 KB static LDS -> 1 block/CU, 8 waves (512 thr) resident.
// Every float4-accessed array is 16B-aligned (ds_read_b128 requirement).
struct __align__(16) Smem {
  alignas(16) float w[4][96*36];   // wih_a, whh_a, wih_m, whh_m ; row stride 36 floats
  alignas(16) float gb[4][96];     // bih_a, bhh_a, bih_m, bhh_m
  alignas(16) float Wxa[6*32], Wxm[4*32];       // [k][32] attri transforms
  alignas(16) float aAll[4][188];  // a_aa/a_am/a_ma/a_mm, 185 used
  alignas(16) float embA[304];     // 9 embedding tables concatenated (300 used)
  alignas(16) float ctxS[NN][2], ctxD[NN][2];   // context part of src/dst logits
  alignas(16) float uSrc[2][2][14];// (Wu[it] @ a[it*2+v][0:32])   [it][v][k]
  alignas(16) float uDst[2][2][14];// (Wu[it] @ a[v*2+it][92:124]) [it][v][k]
  alignas(16) float biasE[NN*56];  // adj_norm*a[184] (or -1e12 where masked)
  alignas(16) float xin[NN*16];    // per-step raw+embedded inputs, 14 used per node
  alignas(16) float attri[NN*32];  // aggregation values
  alignas(16) float srcv[NN*2], dstv[NN*2];
  alignas(16) float p[NN*56];      // attention (unnormalized exp)
  alignas(16) float inv[56];       // 1/rowsum (53 used)
  alignas(16) float gx[NN*32];     // GAT output = GRU input  (float4-read)
  alignas(16) float h[NN*32];      // GRU hidden state        (float4-read)
};

__global__ __launch_bounds__(512, 2)
void chgat_gru_kernel(Params p){
  __shared__ Smem sm;
  const int tid = threadIdx.x;
  const int b = blockIdx.x;

  // ---------------- stage 0: runtime dtype detection ----------------
  bool isbf = false;
  {
    const unsigned* aw = (const unsigned*)p.adj;
    for (int i=0;i<32;++i){
      unsigned w = aw[i];
      if (w != 0u && w != 0x3F800000u) isbf = true;
    }
  }

  // ---------------- stage 1: stage weights into LDS ----------------
  for (int idx=tid; idx<3072; idx+=512) sm.w[0][(idx>>5)*36+(idx&31)] = ldf(p.wih_a, idx, isbf);
  for (int idx=tid; idx<3072; idx+=512) sm.w[1][(idx>>5)*36+(idx&31)] = ldf(p.whh_a, idx, isbf);
  for (int idx=tid; idx<3072; idx+=512) sm.w[2][(idx>>5)*36+(idx&31)] = ldf(p.wih_m, idx, isbf);
  for (int idx=tid; idx<3072; idx+=512) sm.w[3][(idx>>5)*36+(idx&31)] = ldf(p.whh_m, idx, isbf);
  if (tid < 96){
    sm.gb[0][tid]=ldf(p.bih_a,tid,isbf); sm.gb[1][tid]=ldf(p.bhh_a,tid,isbf);
    sm.gb[2][tid]=ldf(p.bih_m,tid,isbf); sm.gb[3][tid]=ldf(p.bhh_m,tid,isbf);
  }
  if (tid < 192) sm.Wxa[tid] = ldf(p.Wxa, tid, isbf);
  if (tid < 128) sm.Wxm[tid] = ldf(p.Wxm, tid, isbf);
  if (tid < 185) sm.aAll[0][tid] = ldf(p.a0, tid, isbf);
  if (tid < 185) sm.aAll[1][tid] = ldf(p.a1, tid, isbf);
  if (tid < 185) sm.aAll[2][tid] = ldf(p.a2, tid, isbf);
  if (tid < 185) sm.aAll[3][tid] = ldf(p.a3, tid, isbf);
  // embeddings: offsets {0,70,96,110,158,176,212,238,252}, total 300
  if (tid < 70)  sm.embA[tid]        = ldf(p.emb0, tid, isbf);
  if (tid < 26)  sm.embA[70+tid]     = ldf(p.emb1, tid, isbf);
  if (tid < 14)  sm.embA[96+tid]     = ldf(p.emb2, tid, isbf);
  if (tid < 48)  sm.embA[110+tid]    = ldf(p.emb3, tid, isbf);
  if (tid < 18)  sm.embA[158+tid]    = ldf(p.emb4, tid, isbf);
  if (tid < 36)  sm.embA[176+tid]    = ldf(p.emb5, tid, isbf);
  if (tid < 26)  sm.embA[212+tid]    = ldf(p.emb6, tid, isbf);
  if (tid < 14)  sm.embA[238+tid]    = ldf(p.emb7, tid, isbf);
  if (tid < 48)  sm.embA[252+tid]    = ldf(p.emb8, tid, isbf);
  for (int idx=tid; idx<NN*32; idx+=512) sm.h[idx] = 0.f;
  __syncthreads();

  // ---------------- stage 2: batch-invariant attention constants ----------------
  if (tid < 212){
    // context half of src/dst logits
    int i = tid>>2, v = tid&3, it = (i<NA)?0:1;
    float s = 0.f;
    if (v < 2){
      const float* ac = &sm.aAll[it*2+v][32];       // a_sel[32..91] · context
      for (int c=0;c<60;++c) s += ldf(p.ctx, i*60+c, isbf)*ac[c];
      sm.ctxS[i][v] = s;
    } else {
      const float* ac = &sm.aAll[(v-2)*2+it][124];  // a_sel[124..183] · context
      for (int c=0;c<60;++c) s += ldf(p.ctx, i*60+c, isbf)*ac[c];
      sm.ctxD[i][v-2] = s;
    }
  } else if (tid < 324){
    // fold Wu into a: uSrc[it][v] = Wu[it] @ a[it*2+v][0:32]
    //                 uDst[it][v] = Wu[it] @ a[v*2+it][92:124]
    int u = tid - 212;                 // 0..111
    int it = u / 56, rem = u % 56;
    int sd = rem / 28, rem2 = rem % 28;
    int v = rem2 / 14, k = rem2 % 14;
    const void* Wu = it ? p.Wum : p.Wua;
    const float* av = sd ? &sm.aAll[v*2+it][92] : &sm.aAll[it*2+v][0];
    float s = 0.f;
    for (int kk=0;kk<32;++kk) s += ldf(Wu, k*32+kk, isbf)*av[kk];
    if (sd) sm.uDst[it][v][k] = s; else sm.uSrc[it][v][k] = s;
  }
  for (int idx=tid; idx<NN*NN; idx+=512){
    int i = idx/NN, j = idx - i*NN;
    int sel = ((i<NA)?0:2) + ((j<NA)?0:1);
    float ad = ldf(p.adj, idx, isbf);
    sm.biasE[i*56+j] = (ad > 0.f) ? ldf(p.adjn, idx, isbf)*sm.aAll[sel][184] : -1e12f;
  }
  __syncthreads();

  // ---------------- prefetch t=0 inputs (exactly 1 load / thread) ----------------
  // slots: 210 aqi raw | 72 meo raw | 140 aqi idx | 90 meo idx = 512
  float rv = 0.f; int ri = 0;
  {
    int bt = b*TT + 0;
    if (tid < 210)      rv = ldf(p.X_aqi, bt*210 + tid, isbf);
    else if (tid < 282) rv = ldf(p.X_meo, bt*72 + tid - 210, isbf);
    else { int u = tid - 282; ri = (u < 140) ? p.Xae[bt*140 + u] : p.Xme[bt*90 + u - 140]; }
  }

  const int s  = tid >> 5;   // 0..15  (node-set for ph4/ph5; n ≡ s mod 16)
  const int dd = tid & 31;   // hidden dim

  for (int t=0; t<TT; ++t){
    // ---- ph0: consume prefetched inputs into xin ----
    if (tid < 210)      sm.xin[(tid/6)*16 + tid%6] = rv;
    else if (tid < 282){ int q = tid-210; sm.xin[(NA + (q>>2))*16 + (q&3)] = rv; }
    else {
      int u = tid - 282;
      if (u < 140){
        int n = u>>2, e = u&3;
        int off = (e==0)?0:(e==1)?70:(e==2)?96:110;
        sm.xin[n*16 + 6 + 2*e]     = sm.embA[off + ri*2];
        sm.xin[n*16 + 6 + 2*e + 1] = sm.embA[off + ri*2 + 1];
      } else {
        int q = u - 140;
        int n = NA + q/5, e = q%5;
        int off = (e==0)?158:(e==1)?176:(e==2)?212:(e==3)?238:252;
        sm.xin[n*16 + 4 + 2*e]     = sm.embA[off + ri*2];
        sm.xin[n*16 + 4 + 2*e + 1] = sm.embA[off + ri*2 + 1];
      }
    }
    // ---- prefetch t+1 ----
    {
      int tn = (t < TT-1) ? t+1 : t;
      int bt = b*TT + tn;
      if (tid < 210)      rv = ldf(p.X_aqi, bt*210 + tid, isbf);
      else if (tid < 282) rv = ldf(p.X_meo, bt*72 + tid - 210, isbf);
      else { int u = tid - 282; ri = (u < 140) ? p.Xae[bt*140 + u] : p.Xme[bt*90 + u - 140]; }
    }
    __syncthreads();   // (1) xin ready

    // ---- ph1: attri = x@Wx (1696 items) + src/dst logits via folded Wu (212 items) ----
    for (int it = tid; it < 1908; it += 512){
      if (it < 1696){
        int n = it>>5, dj = it&31;
        const float* x = &sm.xin[n*16];
        float at = 0.f;
        if (n < NA){
          const float* Wx = sm.Wxa;
          #pragma unroll
          for (int k=0;k<6;++k) at += x[k]*Wx[k*32+dj];
        } else {
          const float* Wx = sm.Wxm;
          #pragma unroll
          for (int k=0;k<4;++k) at += x[k]*Wx[k*32+dj];
        }
        sm.attri[n*32+dj] = at;
      } else {
        int u = it - 1696;               // 0..211
        int i = u>>2, v = u&3, it2 = (i<NA)?0:1;
        const float* x = &sm.xin[i*16];
        float sacc; const float* uv;
        if (v < 2){ sacc = sm.ctxS[i][v];   uv = sm.uSrc[it2][v]; }
        else      { sacc = sm.ctxD[i][v-2]; uv = sm.uDst[it2][v-2]; }
        #pragma unroll
        for (int k=0;k<14;++k) sacc += x[k]*uv[k];
        if (v < 2) sm.srcv[i*2+v] = sacc; else sm.dstv[i*2+(v-2)] = sacc;
      }
    }
    __syncthreads();   // (2) attri, srcv, dstv ready

    // ---- ph3: e = leaky(src+dst+bias), masked softmax (8 lanes/row) ----
    if (tid < 424){
      int i = tid>>3, l = tid&7, it2 = (i<NA)?0:1;
      float s0 = sm.srcv[i*2+0], s1 = sm.srcv[i*2+1];
      float ev[7];
      float mx = -3.0e38f;
      int cnt = 0;
      #pragma unroll
      for (int jj=0; jj<7; ++jj){
        int j = l + jj*8;
        if (j < NN){
          float e = ((j<NA)? s0 : s1) + sm.dstv[j*2+it2] + sm.biasE[i*56+j];
          e = (e >= 0.f) ? e : 0.2f*e;
          ev[jj] = e; mx = fmaxf(mx, e); cnt = jj+1;
        }
      }
      mx = fmaxf(mx, __shfl_xor(mx,1,64));
      mx = fmaxf(mx, __shfl_xor(mx,2,64));
      mx = fmaxf(mx, __shfl_xor(mx,4,64));
      float sum = 0.f;
      #pragma unroll
      for (int jj=0; jj<7; ++jj){
        int j = l + jj*8;
        if (j < NN){
          float pe = __expf(ev[jj] - mx);
          sm.p[i*56+j] = pe;
          sum += pe;
        }
      }
      sum += __shfl_xor(sum,1,64);
      sum += __shfl_xor(sum,2,64);
      sum += __shfl_xor(sum,4,64);
      if (l == 0) sm.inv[i] = 1.0f/sum;
    }
    __syncthreads();   // (3) p, inv ready

    // ---- ph4: gx = softmax(att) @ attri ; rows s, s+16, s+32, (s+48) ----
    {
      float a0=0,a1=0,a2=0,a3=0;
      for (int j=0;j<NN;++j){
        float av = sm.attri[j*32+dd];
        const float* pc = &sm.p[j];
        a0 += pc[(s    )*56]*av;
        a1 += pc[(s+16)*56]*av;
        a2 += pc[(s+32)*56]*av;
        if (s < 5) a3 += pc[(s+48)*56]*av;
      }
      sm.gx[(s    )*32+dd] = a0*sm.inv[s];
      sm.gx[(s+16)*32+dd] = a1*sm.inv[s+16];
      sm.gx[(s+32)*32+dd] = a2*sm.inv[s+32];
      if (s < 5) sm.gx[(s+48)*32+dd] = a3*sm.inv[s+48];
    }
    // NO barrier: gx rows n≡s(16) are written and read by the same half-wave;
    // DS ops from one wave execute in program order.

    // ---- ph5: GRU. thread = (node-set s, dim dd); full k=32 per thread ----
    {
      const bool last = (t == TT-1);
      auto gru = [&](const float* __restrict__ wih, const float* __restrict__ whh,
                     const float* __restrict__ bi,  const float* __restrict__ bh,
                     const int* nodes, int cnt, long long obase, int nbase){
        float ar[3]={0,0,0}, az[3]={0,0,0}, ai_[3]={0,0,0}, ah[3]={0,0,0};
        #pragma unroll
        for (int kq=0;kq<8;++kq){
          int k = kq*4;
          float4 wir = *(const float4*)&wih[(dd   )*36+k];
          float4 wiz = *(const float4*)&wih[(32+dd)*36+k];
          float4 win = *(const float4*)&wih[(64+dd)*36+k];
          float4 whr = *(const float4*)&whh[(dd   )*36+k];
          float4 whz = *(const float4*)&whh[(32+dd)*36+k];
          float4 whn = *(const float4*)&whh[(64+dd)*36+k];
          #pragma unroll
          for (int m=0;m<3;++m){
            if (m >= cnt) break;
            int n = nodes[m];
            float4 x4 = *(const float4*)&sm.gx[n*32+k];
            float4 h4 = *(const float4*)&sm.h[n*32+k];
            ar[m]  += dot4(x4,wir) + dot4(h4,whr);
            az[m]  += dot4(x4,wiz) + dot4(h4,whz);
            ai_[m] += dot4(x4,win);
            ah[m]  += dot4(h4,whn);
          }
        }
        float br = bi[dd]+bh[dd], bz = bi[32+dd]+bh[32+dd];
        float bin = bi[64+dd], bhn = bh[64+dd];
        #pragma unroll
        for (int m=0;m<3;++m){
          if (m >= cnt) break;
          int n = nodes[m];
          float r = 1.f/(1.f+__expf(-(ar[m]+br)));
          float z = 1.f/(1.f+__expf(-(az[m]+bz)));
          float pre = (ai_[m]+bin) + r*(ah[m]+bhn);
          float e2 = __expf(2.f*pre);
          float nn = 1.f - 2.f/(e2+1.f);          // tanh
          float hold = sm.h[n*32+dd];
          float hnew = (1.f-z)*nn + z*hold;
          sm.h[n*32+dd] = hnew;                   // same half-wave rw: no barrier
          if (last){
            long long oi = obase + (long long)(n - nbase)*32 + dd;
            if (isbf) ((__hip_bfloat16*)p.out)[oi] = __float2bfloat16(hnew);
            else      ((float*)p.out)[oi] = hnew;
          }
        }
      };
      int na_[3] = {s, s+16, s+32};
      int cntA = (s<3)?3:2;                 // s+32 < 35 only for s<3
      int nm_[3]; int cntM;
      if (s < 3)      { nm_[0]=s+48; nm_[1]=0; nm_[2]=0; cntM=1; }
      else if (s < 5) { nm_[0]=s+32; nm_[1]=s+48; nm_[2]=0; cntM=2; }
      else            { nm_[0]=s+32; nm_[1]=0; nm_[2]=0; cntM=1; }
      gru(sm.w[0], sm.w[1], sm.gb[0], sm.gb[1], na_, cntA,
          (long long)b*(NA*HH), 0);
      gru(sm.w[2], sm.w[3], sm.gb[2], sm.gb[3], nm_, cntM,
          (long long)OUT_MEO_BASE + (long long)b*(NM*HH), NA);
    }
    // NO barrier at loop end: ph0 touches only xin (disjoint from ph5's gx/h/w),
    // and barrier (1) orders xin against ph1 readers.
  }
}

extern "C" void kernel_launch(void* const* d_in, const int* in_sizes, int n_in,
                              void* d_out, int out_size, void* d_ws, size_t ws_size,
                              hipStream_t stream){
  (void)in_sizes; (void)n_in; (void)d_ws; (void)ws_size; (void)out_size;
  Params p;
  p.X_aqi = d_in[0];
  p.X_meo = d_in[1];
  p.ctx   = d_in[2];
  p.adj   = d_in[3];
  p.adjn  = d_in[4];
  p.emb0 = d_in[5];  p.emb1 = d_in[6];
  p.emb2 = d_in[7];  p.emb3 = d_in[8];
  p.emb4 = d_in[9];  p.emb5 = d_in[10];
  p.emb6 = d_in[11]; p.emb7 = d_in[12];
  p.emb8 = d_in[13];
  p.Wxa = d_in[14]; p.Wxm = d_in[15];
  p.Wua = d_in[16]; p.Wum = d_in[17];
  p.a0 = d_in[18]; p.a1 = d_in[19];
  p.a2 = d_in[20]; p.a3 = d_in[21];
  p.wih_a = d_in[22]; p.whh_a = d_in[23];
  p.bih_a = d_in[24]; p.bhh_a = d_in[25];
  p.wih_m = d_in[26]; p.whh_m = d_in[27];
  p.bih_m = d_in[28]; p.bhh_m = d_in[29];
  p.Xae = (const int*)d_in[30];
  p.Xme = (const int*)d_in[31];
  p.out = d_out;
  hipLaunchKernelGGL(chgat_gru_kernel, dim3(1024), dim3(512), 0, stream, p);
}